// Round 14
// baseline (87.137 us; speedup 1.0000x reference)
//
#include <hip/hip_runtime.h>
#include <hip/hip_bf16.h>
#include <hip/hip_fp16.h>

#define NTOK 2048
#define DDIM 512
#define NBATCH 8

using bf16x8 = __attribute__((ext_vector_type(8))) short;
using f32x4  = __attribute__((ext_vector_type(4))) float;

__device__ __forceinline__ short f2bf(float f) {
  __hip_bfloat16 h = __float2bfloat16(f);
  union { __hip_bfloat16 h; short s; } u; u.h = h;
  return u.s;
}

__device__ __forceinline__ float e5m2tof(unsigned byte) {
  // e5m2 is f16 truncated to its top 8 bits
  union { unsigned short u; __half h; } c;
  c.u = (unsigned short)(byte << 8);
  return __half2float(c.h);
}

__device__ __forceinline__ void async_copy16(void* lds, const void* g) {
  __builtin_amdgcn_global_load_lds(
      (const __attribute__((address_space(1))) void*)g,
      (__attribute__((address_space(3))) void*)lds,
      16, 0, 0);
}

// fp32 -> fp8 e4m3 (OCP) convert: each thread 8 floats -> 8 B store.
__global__ __launch_bounds__(256) void convert_fp8_kernel(const float* __restrict__ X,
                                                          char* __restrict__ Y) {
  const int i = blockIdx.x * 256 + threadIdx.x;
  const float4* xv = reinterpret_cast<const float4*>(X);
  const float4 a = xv[(size_t)i * 2];
  const float4 b = xv[(size_t)i * 2 + 1];
  int lo = __builtin_amdgcn_cvt_pk_fp8_f32(a.x, a.y, 0, false);
  lo     = __builtin_amdgcn_cvt_pk_fp8_f32(a.z, a.w, lo, true);
  int hi = __builtin_amdgcn_cvt_pk_fp8_f32(b.x, b.y, 0, false);
  hi     = __builtin_amdgcn_cvt_pk_fp8_f32(b.z, b.w, hi, true);
  int2 o; o.x = lo; o.y = hi;
  *reinterpret_cast<int2*>(Y + (size_t)i * 8) = o;
}

// Symmetric scores on fp8-e4m3 inputs. 128x128 tile, 4 waves (2Mx2N),
// BK=64 double-buffered (8 K-steps -> HALF the barrier/vmcnt events of r13's
// BK=32; r12 A/B showed stalls are ~70% of scores cost). 32 KB LDS ->
// 4 blocks/CU. Depth-2 prefetch, counted vmcnt. Output S in fp8-e5m2
// (halves S write + softmax read; one-hot margin analysis in round notes).
__global__ __launch_bounds__(256, 4) void scores_fp8_kernel(
    const char* __restrict__ X8, char* __restrict__ S8) {
  int rem = blockIdx.x >> 3;
  int bi = 0;
  while (rem >= 16 - bi) { rem -= 16 - bi; ++bi; }
  const int bj = bi + rem;
  const int b  = blockIdx.x & 7;           // batch -> XCD pin
  const bool diag = (bi == bj);

  const int i0 = bi * 128;
  const int j0 = bj * 128;
  const char* Xb = X8 + (size_t)b * NTOK * DDIM;   // 512 B per row
  char* Sb = S8 + (size_t)b * NTOK * NTOK;         // 1 B per score

  __shared__ char ldsA8[2][128 * 64];      // 8 KB per buf
  __shared__ char ldsB8[2][128 * 64];      // total 32 KB

  const int t    = threadIdx.x;
  const int lane = t & 63;
  const int w    = t >> 6;                 // 0..3
  const int wr   = (w >> 1) * 64;
  const int wc   = (w & 1) * 64;
  const int lr   = lane & 15;
  const int lk8  = (lane >> 4) * 8;        // 8 fp8 elements (8 B)

  f32x4 acc[4][4] = {};

  auto stage8 = [&](int buf, int kt) {
    const int k0 = kt * 64;                // 64 B per row per K-step
#pragma unroll
    for (int q = 0; q < 2; ++q) {
      const int seg = w * 2 + q;           // 8 segs of 1 KB (16 rows x 64 B)
      const int row = seg * 16 + (lane >> 2);
      const int cb  = (lane & 3) * 16;
      async_copy16(&ldsA8[buf][seg * 1024],
                   Xb + (size_t)(i0 + row) * DDIM + k0 + cb);
      if (!diag)
        async_copy16(&ldsB8[buf][seg * 1024],
                     Xb + (size_t)(j0 + row) * DDIM + k0 + cb);
    }
  };

  auto phases8 = [&](int buf) {
    const char* A0 = ldsA8[buf];
    const char* B0 = diag ? ldsA8[buf] : ldsB8[buf];
#pragma unroll
    for (int ks = 0; ks < 2; ++ks) {
      const int ko = ks * 32 + lk8;
      long long af0 = *reinterpret_cast<const long long*>(&A0[(wr + 0 * 16 + lr) * 64 + ko]);
      long long af1 = *reinterpret_cast<const long long*>(&A0[(wr + 1 * 16 + lr) * 64 + ko]);
      long long af2 = *reinterpret_cast<const long long*>(&A0[(wr + 2 * 16 + lr) * 64 + ko]);
      long long af3 = *reinterpret_cast<const long long*>(&A0[(wr + 3 * 16 + lr) * 64 + ko]);
      long long bf0 = *reinterpret_cast<const long long*>(&B0[(wc + 0 * 16 + lr) * 64 + ko]);
      long long bf1 = *reinterpret_cast<const long long*>(&B0[(wc + 1 * 16 + lr) * 64 + ko]);
      long long bf2 = *reinterpret_cast<const long long*>(&B0[(wc + 2 * 16 + lr) * 64 + ko]);
      long long bf3 = *reinterpret_cast<const long long*>(&B0[(wc + 3 * 16 + lr) * 64 + ko]);
      __builtin_amdgcn_s_setprio(1);
      acc[0][0] = __builtin_amdgcn_mfma_f32_16x16x32_fp8_fp8(af0, bf0, acc[0][0], 0, 0, 0);
      acc[0][1] = __builtin_amdgcn_mfma_f32_16x16x32_fp8_fp8(af0, bf1, acc[0][1], 0, 0, 0);
      acc[0][2] = __builtin_amdgcn_mfma_f32_16x16x32_fp8_fp8(af0, bf2, acc[0][2], 0, 0, 0);
      acc[0][3] = __builtin_amdgcn_mfma_f32_16x16x32_fp8_fp8(af0, bf3, acc[0][3], 0, 0, 0);
      acc[1][0] = __builtin_amdgcn_mfma_f32_16x16x32_fp8_fp8(af1, bf0, acc[1][0], 0, 0, 0);
      acc[1][1] = __builtin_amdgcn_mfma_f32_16x16x32_fp8_fp8(af1, bf1, acc[1][1], 0, 0, 0);
      acc[1][2] = __builtin_amdgcn_mfma_f32_16x16x32_fp8_fp8(af1, bf2, acc[1][2], 0, 0, 0);
      acc[1][3] = __builtin_amdgcn_mfma_f32_16x16x32_fp8_fp8(af1, bf3, acc[1][3], 0, 0, 0);
      acc[2][0] = __builtin_amdgcn_mfma_f32_16x16x32_fp8_fp8(af2, bf0, acc[2][0], 0, 0, 0);
      acc[2][1] = __builtin_amdgcn_mfma_f32_16x16x32_fp8_fp8(af2, bf1, acc[2][1], 0, 0, 0);
      acc[2][2] = __builtin_amdgcn_mfma_f32_16x16x32_fp8_fp8(af2, bf2, acc[2][2], 0, 0, 0);
      acc[2][3] = __builtin_amdgcn_mfma_f32_16x16x32_fp8_fp8(af2, bf3, acc[2][3], 0, 0, 0);
      acc[3][0] = __builtin_amdgcn_mfma_f32_16x16x32_fp8_fp8(af3, bf0, acc[3][0], 0, 0, 0);
      acc[3][1] = __builtin_amdgcn_mfma_f32_16x16x32_fp8_fp8(af3, bf1, acc[3][1], 0, 0, 0);
      acc[3][2] = __builtin_amdgcn_mfma_f32_16x16x32_fp8_fp8(af3, bf2, acc[3][2], 0, 0, 0);
      acc[3][3] = __builtin_amdgcn_mfma_f32_16x16x32_fp8_fp8(af3, bf3, acc[3][3], 0, 0, 0);
      __builtin_amdgcn_s_setprio(0);
    }
  };

  stage8(0, 0);
#pragma unroll
  for (int i = 0; i < 7; ++i) {
    stage8((i + 1) & 1, i + 1);
    if (diag) { asm volatile("s_waitcnt vmcnt(2)" ::: "memory"); }
    else      { asm volatile("s_waitcnt vmcnt(4)" ::: "memory"); }
    __builtin_amdgcn_s_barrier();
    phases8(i & 1);
    __builtin_amdgcn_s_barrier();
  }
  asm volatile("s_waitcnt vmcnt(0)" ::: "memory");
  __builtin_amdgcn_s_barrier();
  phases8(1);

  // epilogue: C/D layout col = lane&15, row = (lane>>4)*4 + reg
  // pack 4 rows' values to e5m2 -> byte stores (normal), int store (mirror)
  const int crow = (lane >> 4) * 4;
  const int ccol = lane & 15;

#pragma unroll
  for (int m = 0; m < 4; ++m) {
#pragma unroll
    for (int n = 0; n < 4; ++n) {
      const int gr = i0 + wr + m * 16 + crow;   // multiple of 4
      const int gc = j0 + wc + n * 16 + ccol;
      int pk = __builtin_amdgcn_cvt_pk_bf8_f32(acc[m][n][0], acc[m][n][1], 0, false);
      pk     = __builtin_amdgcn_cvt_pk_bf8_f32(acc[m][n][2], acc[m][n][3], pk, true);
      Sb[(size_t)(gr + 0) * NTOK + gc] = (char)(pk & 0xff);
      Sb[(size_t)(gr + 1) * NTOK + gc] = (char)((pk >> 8) & 0xff);
      Sb[(size_t)(gr + 2) * NTOK + gc] = (char)((pk >> 16) & 0xff);
      Sb[(size_t)(gr + 3) * NTOK + gc] = (char)((pk >> 24) & 0xff);
      if (!diag) {
        // mirror: 4 consecutive cols at row gc -> one aligned int store
        *reinterpret_cast<int*>(Sb + (size_t)gc * NTOK + gr) = pk;
      }
    }
  }
}

// Row softmax: e5m2 scores in, fp32 probabilities out.
// One 256-thread block per row; thread t owns cols [t*8, t*8+8).
__global__ __launch_bounds__(256) void softmax_fp8_kernel(
    const char* __restrict__ S8, float* __restrict__ P) {
  const int b   = blockIdx.x & 7;
  const int row = blockIdx.x >> 3;
  const char* srow = S8 + ((size_t)b * NTOK + row) * NTOK;
  float* prow = P + ((size_t)b * NTOK + row) * NTOK;

  const int t    = threadIdx.x;
  const int lane = t & 63;
  const int w    = t >> 6;

  const int2 h = *reinterpret_cast<const int2*>(srow + t * 8);
  const unsigned lo = (unsigned)h.x, hi = (unsigned)h.y;
  float v[8];
#pragma unroll
  for (int k = 0; k < 4; ++k) {
    v[k]     = e5m2tof((lo >> (8 * k)) & 0xff);
    v[k + 4] = e5m2tof((hi >> (8 * k)) & 0xff);
  }

  float m = v[0];
#pragma unroll
  for (int k = 1; k < 8; ++k) m = fmaxf(m, v[k]);
#pragma unroll
  for (int off = 32; off > 0; off >>= 1) m = fmaxf(m, __shfl_xor(m, off));

  __shared__ float redm[4];
  __shared__ float reds[4];
  if (lane == 0) redm[w] = m;
  __syncthreads();
  m = fmaxf(fmaxf(redm[0], redm[1]), fmaxf(redm[2], redm[3]));

  float s = 0.f;
#pragma unroll
  for (int k = 0; k < 8; ++k) { v[k] = __expf(v[k] - m); s += v[k]; }
#pragma unroll
  for (int off = 32; off > 0; off >>= 1) s += __shfl_xor(s, off);
  if (lane == 0) reds[w] = s;
  __syncthreads();
  s = reds[0] + reds[1] + reds[2] + reds[3];

  const float inv = 1.0f / s;
  f32x4 o0, o1;
#pragma unroll
  for (int k = 0; k < 4; ++k) { o0[k] = v[k] * inv; o1[k] = v[k + 4] * inv; }
  *reinterpret_cast<f32x4*>(prow + t * 8)     = o0;
  *reinterpret_cast<f32x4*>(prow + t * 8 + 4) = o1;
}

// ---------- fallback path (ws too small): round-1 verified kernels ----------
__global__ __launch_bounds__(256) void scores_kernel(const float* __restrict__ X,
                                                     float* __restrict__ S) {
  const int b  = blockIdx.z;
  const int i0 = blockIdx.y * 128;
  const int j0 = blockIdx.x * 128;
  const float* Xb = X + (size_t)b * NTOK * DDIM;
  float* Sb = S + (size_t)b * NTOK * NTOK;

  __shared__ short lds_a[128][64];
  __shared__ short lds_b[128][64];

  const int t    = threadIdx.x;
  const int lane = t & 63;
  const int w    = t >> 6;
  const int wr   = (w >> 1) * 64;
  const int wc   = (w & 1) * 64;
  const int lr   = lane & 15;
  const int lk   = (lane >> 4) * 8;

  f32x4 acc[4][4] = {};

  for (int k0 = 0; k0 < DDIM; k0 += 64) {
#pragma unroll
    for (int q = 0; q < 8; ++q) {
      const int v  = t + 256 * q;
      const int r  = v >> 4;
      const int c4 = (v & 15) * 4;
      const float4 va = *reinterpret_cast<const float4*>(
          Xb + (size_t)(i0 + r) * DDIM + k0 + c4);
      const float4 vb = *reinterpret_cast<const float4*>(
          Xb + (size_t)(j0 + r) * DDIM + k0 + c4);
      short4 sa, sb;
      sa.x = f2bf(va.x); sa.y = f2bf(va.y); sa.z = f2bf(va.z); sa.w = f2bf(va.w);
      sb.x = f2bf(vb.x); sb.y = f2bf(vb.y); sb.z = f2bf(vb.z); sb.w = f2bf(vb.w);
      *reinterpret_cast<short4*>(&lds_a[r][c4]) = sa;
      *reinterpret_cast<short4*>(&lds_b[r][c4]) = sb;
    }
    __syncthreads();

#pragma unroll
    for (int ks = 0; ks < 2; ++ks) {
      bf16x8 af[4], bfr[4];
#pragma unroll
      for (int m = 0; m < 4; ++m)
        af[m] = *reinterpret_cast<const bf16x8*>(&lds_a[wr + m * 16 + lr][ks * 32 + lk]);
#pragma unroll
      for (int n = 0; n < 4; ++n)
        bfr[n] = *reinterpret_cast<const bf16x8*>(&lds_b[wc + n * 16 + lr][ks * 32 + lk]);
#pragma unroll
      for (int m = 0; m < 4; ++m)
#pragma unroll
        for (int n = 0; n < 4; ++n)
          acc[m][n] = __builtin_amdgcn_mfma_f32_16x16x32_bf16(af[m], bfr[n], acc[m][n], 0, 0, 0);
    }
    __syncthreads();
  }

  const int crow = (lane >> 4) * 4;
  const int ccol = lane & 15;
#pragma unroll
  for (int m = 0; m < 4; ++m) {
#pragma unroll
    for (int n = 0; n < 4; ++n) {
      const int gr = i0 + wr + m * 16 + crow;
      const int gc = j0 + wc + n * 16 + ccol;
      float* outp = Sb + (size_t)gr * NTOK + gc;
#pragma unroll
      for (int r = 0; r < 4; ++r)
        outp[(size_t)r * NTOK] = acc[m][n][r];
    }
  }
}

// In-place row softmax: one 256-thread block per row of 2048 fp32.
__global__ __launch_bounds__(256) void softmax_kernel(float* __restrict__ S) {
  float* row = S + (size_t)blockIdx.x * NTOK;
  const int t    = threadIdx.x;
  const int lane = t & 63;
  const int w    = t >> 6;

  float4* rv = reinterpret_cast<float4*>(row);
  float4 a = rv[t];
  float4 b = rv[t + 256];

  float m = fmaxf(fmaxf(fmaxf(a.x, a.y), fmaxf(a.z, a.w)),
                  fmaxf(fmaxf(b.x, b.y), fmaxf(b.z, b.w)));
#pragma unroll
  for (int off = 32; off > 0; off >>= 1) m = fmaxf(m, __shfl_xor(m, off));

  __shared__ float redm[4];
  __shared__ float reds[4];
  if (lane == 0) redm[w] = m;
  __syncthreads();
  m = fmaxf(fmaxf(redm[0], redm[1]), fmaxf(redm[2], redm[3]));

  a.x = __expf(a.x - m); a.y = __expf(a.y - m);
  a.z = __expf(a.z - m); a.w = __expf(a.w - m);
  b.x = __expf(b.x - m); b.y = __expf(b.y - m);
  b.z = __expf(b.z - m); b.w = __expf(b.w - m);

  float s = (a.x + a.y + a.z + a.w) + (b.x + b.y + b.z + b.w);
#pragma unroll
  for (int off = 32; off > 0; off >>= 1) s += __shfl_xor(s, off);
  if (lane == 0) reds[w] = s;
  __syncthreads();
  s = reds[0] + reds[1] + reds[2] + reds[3];

  const float inv = 1.0f / s;
  a.x *= inv; a.y *= inv; a.z *= inv; a.w *= inv;
  b.x *= inv; b.y *= inv; b.z *= inv; b.w *= inv;
  rv[t] = a;
  rv[t + 256] = b;
}

extern "C" void kernel_launch(void* const* d_in, const int* in_sizes, int n_in,
                              void* d_out, int out_size, void* d_ws, size_t ws_size,
                              hipStream_t stream) {
  const float* X = (const float*)d_in[0];
  float* out = (float*)d_out;

  const size_t offS = 32u << 20;   // S8 at +32 MB (X8 is 8.4 MB)
  const size_t need = offS + (size_t)NBATCH * NTOK * NTOK;  // ~66 MB

  if (ws_size >= need) {
    char* X8 = (char*)d_ws;
    char* S8 = (char*)d_ws + offS;
    const int n_threads = NBATCH * NTOK * DDIM / 8;
    convert_fp8_kernel<<<n_threads / 256, 256, 0, stream>>>(X, X8);
    // 136 triangular 128x128 tiles x 8 batches; bid&7 = batch (XCD pin)
    scores_fp8_kernel<<<136 * NBATCH, 256, 0, stream>>>(X8, S8);
    softmax_fp8_kernel<<<NBATCH * NTOK, 256, 0, stream>>>(S8, out);
  } else {
    dim3 ggrid(NTOK / 128, NTOK / 128, NBATCH);
    scores_kernel<<<ggrid, 256, 0, stream>>>(X, out);
    softmax_kernel<<<NBATCH * NTOK, 256, 0, stream>>>(out);
  }
}

// Round 15
// 69.806 us; speedup vs baseline: 1.2483x; 1.2483x over previous
//
#include <hip/hip_runtime.h>
#include <hip/hip_bf16.h>

#define NTOK 2048
#define DDIM 512
#define NBATCH 8

using bf16x8 = __attribute__((ext_vector_type(8))) short;
using f32x4  = __attribute__((ext_vector_type(4))) float;

__device__ __forceinline__ short f2bf(float f) {
  __hip_bfloat16 h = __float2bfloat16(f);
  union { __hip_bfloat16 h; short s; } u; u.h = h;
  return u.s;
}

__device__ __forceinline__ float bf2f(short s) {
  union { unsigned u; float f; } u;
  u.u = ((unsigned)(unsigned short)s) << 16;
  return u.f;
}

__device__ __forceinline__ void async_copy16(void* lds, const void* g) {
  __builtin_amdgcn_global_load_lds(
      (const __attribute__((address_space(1))) void*)g,
      (__attribute__((address_space(3))) void*)lds,
      16, 0, 0);
}

// fp32 -> fp8 e4m3 (OCP) convert: each thread 8 floats -> 8 B store.
__global__ __launch_bounds__(256) void convert_fp8_kernel(const float* __restrict__ X,
                                                          char* __restrict__ Y) {
  const int i = blockIdx.x * 256 + threadIdx.x;
  const float4* xv = reinterpret_cast<const float4*>(X);
  const float4 a = xv[(size_t)i * 2];
  const float4 b = xv[(size_t)i * 2 + 1];
  int lo = __builtin_amdgcn_cvt_pk_fp8_f32(a.x, a.y, 0, false);
  lo     = __builtin_amdgcn_cvt_pk_fp8_f32(a.z, a.w, lo, true);
  int hi = __builtin_amdgcn_cvt_pk_fp8_f32(b.x, b.y, 0, false);
  hi     = __builtin_amdgcn_cvt_pk_fp8_f32(b.z, b.w, hi, true);
  int2 o; o.x = lo; o.y = hi;
  *reinterpret_cast<int2*>(Y + (size_t)i * 8) = o;
}

// Symmetric scores on fp8-e4m3. 128x128 tile, 4 waves (2Mx2N), BK=64
// double-buffered (8 K-steps = half the barrier/vmcnt events of r13's BK=32),
// WITH 16B-chunk XOR swizzle so the BK=64 bank conflict (8-way, the r14
// regression) never appears: linear LDS dest (global_load_lds requirement),
// global source chunk pre-swizzled by (lane&3)^((row>>2)&3), ds_read offset
// swizzled by the same involution (two per-thread constants). <=2-way bank
// aliasing = free. Output S in bf16 (r13-verified epilogue). Diag alias B->A.
__global__ __launch_bounds__(256, 4) void scores_fp8_kernel(
    const char* __restrict__ X8, short* __restrict__ S16) {
  int rem = blockIdx.x >> 3;
  int bi = 0;
  while (rem >= 16 - bi) { rem -= 16 - bi; ++bi; }
  const int bj = bi + rem;
  const int b  = blockIdx.x & 7;           // batch -> XCD pin
  const bool diag = (bi == bj);

  const int i0 = bi * 128;
  const int j0 = bj * 128;
  const char* Xb = X8 + (size_t)b * NTOK * DDIM;   // 512 B per row
  short* Sb = S16 + (size_t)b * NTOK * NTOK;

  __shared__ char ldsA8[2][128 * 64];      // 8 KB per buf
  __shared__ char ldsB8[2][128 * 64];      // total 32 KB

  const int t    = threadIdx.x;
  const int lane = t & 63;
  const int w    = t >> 6;                 // 0..3
  const int wr   = (w >> 1) * 64;
  const int wc   = (w & 1) * 64;
  const int lr   = lane & 15;
  const int g    = lane >> 4;              // 0..3
  const int s4   = (lr >> 2) & 3;          // read-side swizzle key (row>>2)&3
  // swizzled per-thread read offsets for ks = 0,1 (global chunk -> LDS chunk)
  const int ko0  = (((g >> 1) ^ s4) * 16) + (g & 1) * 8;
  const int ko1  = (((2 + (g >> 1)) ^ s4) * 16) + (g & 1) * 8;

  f32x4 acc[4][4] = {};

  auto stage8 = [&](int buf, int kt) {
    const int k0 = kt * 64;                // 64 B per row per K-step
#pragma unroll
    for (int q = 0; q < 2; ++q) {
      const int seg  = w * 2 + q;          // 8 segs of 1 KB (16 rows x 64 B)
      const int row  = seg * 16 + (lane >> 2);
      const int csrc = ((lane & 3) ^ ((row >> 2) & 3)) * 16;  // inverse swizzle
      async_copy16(&ldsA8[buf][seg * 1024],
                   Xb + (size_t)(i0 + row) * DDIM + k0 + csrc);
      if (!diag)
        async_copy16(&ldsB8[buf][seg * 1024],
                     Xb + (size_t)(j0 + row) * DDIM + k0 + csrc);
    }
  };

  auto phases8 = [&](int buf) {
    const char* A0 = ldsA8[buf];
    const char* B0 = diag ? ldsA8[buf] : ldsB8[buf];
#pragma unroll
    for (int ks = 0; ks < 2; ++ks) {
      const int ko = ks ? ko1 : ko0;
      long long af0 = *reinterpret_cast<const long long*>(&A0[(wr + 0 * 16 + lr) * 64 + ko]);
      long long af1 = *reinterpret_cast<const long long*>(&A0[(wr + 1 * 16 + lr) * 64 + ko]);
      long long af2 = *reinterpret_cast<const long long*>(&A0[(wr + 2 * 16 + lr) * 64 + ko]);
      long long af3 = *reinterpret_cast<const long long*>(&A0[(wr + 3 * 16 + lr) * 64 + ko]);
      long long bf0 = *reinterpret_cast<const long long*>(&B0[(wc + 0 * 16 + lr) * 64 + ko]);
      long long bf1 = *reinterpret_cast<const long long*>(&B0[(wc + 1 * 16 + lr) * 64 + ko]);
      long long bf2 = *reinterpret_cast<const long long*>(&B0[(wc + 2 * 16 + lr) * 64 + ko]);
      long long bf3 = *reinterpret_cast<const long long*>(&B0[(wc + 3 * 16 + lr) * 64 + ko]);
      __builtin_amdgcn_s_setprio(1);
      acc[0][0] = __builtin_amdgcn_mfma_f32_16x16x32_fp8_fp8(af0, bf0, acc[0][0], 0, 0, 0);
      acc[0][1] = __builtin_amdgcn_mfma_f32_16x16x32_fp8_fp8(af0, bf1, acc[0][1], 0, 0, 0);
      acc[0][2] = __builtin_amdgcn_mfma_f32_16x16x32_fp8_fp8(af0, bf2, acc[0][2], 0, 0, 0);
      acc[0][3] = __builtin_amdgcn_mfma_f32_16x16x32_fp8_fp8(af0, bf3, acc[0][3], 0, 0, 0);
      acc[1][0] = __builtin_amdgcn_mfma_f32_16x16x32_fp8_fp8(af1, bf0, acc[1][0], 0, 0, 0);
      acc[1][1] = __builtin_amdgcn_mfma_f32_16x16x32_fp8_fp8(af1, bf1, acc[1][1], 0, 0, 0);
      acc[1][2] = __builtin_amdgcn_mfma_f32_16x16x32_fp8_fp8(af1, bf2, acc[1][2], 0, 0, 0);
      acc[1][3] = __builtin_amdgcn_mfma_f32_16x16x32_fp8_fp8(af1, bf3, acc[1][3], 0, 0, 0);
      acc[2][0] = __builtin_amdgcn_mfma_f32_16x16x32_fp8_fp8(af2, bf0, acc[2][0], 0, 0, 0);
      acc[2][1] = __builtin_amdgcn_mfma_f32_16x16x32_fp8_fp8(af2, bf1, acc[2][1], 0, 0, 0);
      acc[2][2] = __builtin_amdgcn_mfma_f32_16x16x32_fp8_fp8(af2, bf2, acc[2][2], 0, 0, 0);
      acc[2][3] = __builtin_amdgcn_mfma_f32_16x16x32_fp8_fp8(af2, bf3, acc[2][3], 0, 0, 0);
      acc[3][0] = __builtin_amdgcn_mfma_f32_16x16x32_fp8_fp8(af3, bf0, acc[3][0], 0, 0, 0);
      acc[3][1] = __builtin_amdgcn_mfma_f32_16x16x32_fp8_fp8(af3, bf1, acc[3][1], 0, 0, 0);
      acc[3][2] = __builtin_amdgcn_mfma_f32_16x16x32_fp8_fp8(af3, bf2, acc[3][2], 0, 0, 0);
      acc[3][3] = __builtin_amdgcn_mfma_f32_16x16x32_fp8_fp8(af3, bf3, acc[3][3], 0, 0, 0);
      __builtin_amdgcn_s_setprio(0);
    }
  };

  stage8(0, 0);
#pragma unroll
  for (int i = 0; i < 7; ++i) {
    stage8((i + 1) & 1, i + 1);
    if (diag) { asm volatile("s_waitcnt vmcnt(2)" ::: "memory"); }
    else      { asm volatile("s_waitcnt vmcnt(4)" ::: "memory"); }
    __builtin_amdgcn_s_barrier();
    phases8(i & 1);
    __builtin_amdgcn_s_barrier();
  }
  asm volatile("s_waitcnt vmcnt(0)" ::: "memory");
  __builtin_amdgcn_s_barrier();
  phases8(1);

  // epilogue (r13-verified): C/D layout col = lane&15, row = (lane>>4)*4 + reg
  const int crow = (lane >> 4) * 4;
  const int ccol = lane & 15;

#pragma unroll
  for (int m = 0; m < 4; ++m) {
#pragma unroll
    for (int n = 0; n < 4; ++n) {
      const int gr = i0 + wr + m * 16 + crow;
      const int gc = j0 + wc + n * 16 + ccol;
      short4 pv;
      pv.x = f2bf(acc[m][n][0]);
      pv.y = f2bf(acc[m][n][1]);
      pv.z = f2bf(acc[m][n][2]);
      pv.w = f2bf(acc[m][n][3]);
      Sb[(size_t)(gr + 0) * NTOK + gc] = pv.x;
      Sb[(size_t)(gr + 1) * NTOK + gc] = pv.y;
      Sb[(size_t)(gr + 2) * NTOK + gc] = pv.z;
      Sb[(size_t)(gr + 3) * NTOK + gc] = pv.w;
      if (!diag) {
        *reinterpret_cast<short4*>(Sb + (size_t)gc * NTOK + gr) = pv;
      }
    }
  }
}

// Row softmax: bf16 scores in, fp32 probabilities out (r13-verified).
__global__ __launch_bounds__(256) void softmax_bf16_kernel(
    const short* __restrict__ S16, float* __restrict__ P) {
  const int b   = blockIdx.x & 7;
  const int row = blockIdx.x >> 3;
  const short* srow = S16 + ((size_t)b * NTOK + row) * NTOK;
  float* prow = P + ((size_t)b * NTOK + row) * NTOK;

  const int t    = threadIdx.x;
  const int lane = t & 63;
  const int w    = t >> 6;

  const bf16x8 h = *reinterpret_cast<const bf16x8*>(srow + t * 8);
  float v[8];
#pragma unroll
  for (int k = 0; k < 8; ++k) v[k] = bf2f(h[k]);

  float m = v[0];
#pragma unroll
  for (int k = 1; k < 8; ++k) m = fmaxf(m, v[k]);
#pragma unroll
  for (int off = 32; off > 0; off >>= 1) m = fmaxf(m, __shfl_xor(m, off));

  __shared__ float redm[4];
  __shared__ float reds[4];
  if (lane == 0) redm[w] = m;
  __syncthreads();
  m = fmaxf(fmaxf(redm[0], redm[1]), fmaxf(redm[2], redm[3]));

  float s = 0.f;
#pragma unroll
  for (int k = 0; k < 8; ++k) { v[k] = __expf(v[k] - m); s += v[k]; }
#pragma unroll
  for (int off = 32; off > 0; off >>= 1) s += __shfl_xor(s, off);
  if (lane == 0) reds[w] = s;
  __syncthreads();
  s = reds[0] + reds[1] + reds[2] + reds[3];

  const float inv = 1.0f / s;
  f32x4 o0, o1;
#pragma unroll
  for (int k = 0; k < 4; ++k) { o0[k] = v[k] * inv; o1[k] = v[k + 4] * inv; }
  *reinterpret_cast<f32x4*>(prow + t * 8)     = o0;
  *reinterpret_cast<f32x4*>(prow + t * 8 + 4) = o1;
}

// ---------- fallback path (ws too small): round-1 verified kernels ----------
__global__ __launch_bounds__(256) void scores_kernel(const float* __restrict__ X,
                                                     float* __restrict__ S) {
  const int b  = blockIdx.z;
  const int i0 = blockIdx.y * 128;
  const int j0 = blockIdx.x * 128;
  const float* Xb = X + (size_t)b * NTOK * DDIM;
  float* Sb = S + (size_t)b * NTOK * NTOK;

  __shared__ short lds_a[128][64];
  __shared__ short lds_b[128][64];

  const int t    = threadIdx.x;
  const int lane = t & 63;
  const int w    = t >> 6;
  const int wr   = (w >> 1) * 64;
  const int wc   = (w & 1) * 64;
  const int lr   = lane & 15;
  const int lk   = (lane >> 4) * 8;

  f32x4 acc[4][4] = {};

  for (int k0 = 0; k0 < DDIM; k0 += 64) {
#pragma unroll
    for (int q = 0; q < 8; ++q) {
      const int v  = t + 256 * q;
      const int r  = v >> 4;
      const int c4 = (v & 15) * 4;
      const float4 va = *reinterpret_cast<const float4*>(
          Xb + (size_t)(i0 + r) * DDIM + k0 + c4);
      const float4 vb = *reinterpret_cast<const float4*>(
          Xb + (size_t)(j0 + r) * DDIM + k0 + c4);
      short4 sa, sb;
      sa.x = f2bf(va.x); sa.y = f2bf(va.y); sa.z = f2bf(va.z); sa.w = f2bf(va.w);
      sb.x = f2bf(vb.x); sb.y = f2bf(vb.y); sb.z = f2bf(vb.z); sb.w = f2bf(vb.w);
      *reinterpret_cast<short4*>(&lds_a[r][c4]) = sa;
      *reinterpret_cast<short4*>(&lds_b[r][c4]) = sb;
    }
    __syncthreads();

#pragma unroll
    for (int ks = 0; ks < 2; ++ks) {
      bf16x8 af[4], bfr[4];
#pragma unroll
      for (int m = 0; m < 4; ++m)
        af[m] = *reinterpret_cast<const bf16x8*>(&lds_a[wr + m * 16 + lr][ks * 32 + lk]);
#pragma unroll
      for (int n = 0; n < 4; ++n)
        bfr[n] = *reinterpret_cast<const bf16x8*>(&lds_b[wc + n * 16 + lr][ks * 32 + lk]);
#pragma unroll
      for (int m = 0; m < 4; ++m)
#pragma unroll
        for (int n = 0; n < 4; ++n)
          acc[m][n] = __builtin_amdgcn_mfma_f32_16x16x32_bf16(af[m], bfr[n], acc[m][n], 0, 0, 0);
    }
    __syncthreads();
  }

  const int crow = (lane >> 4) * 4;
  const int ccol = lane & 15;
#pragma unroll
  for (int m = 0; m < 4; ++m) {
#pragma unroll
    for (int n = 0; n < 4; ++n) {
      const int gr = i0 + wr + m * 16 + crow;
      const int gc = j0 + wc + n * 16 + ccol;
      float* outp = Sb + (size_t)gr * NTOK + gc;
#pragma unroll
      for (int r = 0; r < 4; ++r)
        outp[(size_t)r * NTOK] = acc[m][n][r];
    }
  }
}

// In-place row softmax: one 256-thread block per row of 2048 fp32.
__global__ __launch_bounds__(256) void softmax_kernel(float* __restrict__ S) {
  float* row = S + (size_t)blockIdx.x * NTOK;
  const int t    = threadIdx.x;
  const int lane = t & 63;
  const int w    = t >> 6;

  float4* rv = reinterpret_cast<float4*>(row);
  float4 a = rv[t];
  float4 b = rv[t + 256];

  float m = fmaxf(fmaxf(fmaxf(a.x, a.y), fmaxf(a.z, a.w)),
                  fmaxf(fmaxf(b.x, b.y), fmaxf(b.z, b.w)));
#pragma unroll
  for (int off = 32; off > 0; off >>= 1) m = fmaxf(m, __shfl_xor(m, off));

  __shared__ float redm[4];
  __shared__ float reds[4];
  if (lane == 0) redm[w] = m;
  __syncthreads();
  m = fmaxf(fmaxf(redm[0], redm[1]), fmaxf(redm[2], redm[3]));

  a.x = __expf(a.x - m); a.y = __expf(a.y - m);
  a.z = __expf(a.z - m); a.w = __expf(a.w - m);
  b.x = __expf(b.x - m); b.y = __expf(b.y - m);
  b.z = __expf(b.z - m); b.w = __expf(b.w - m);

  float s = (a.x + a.y + a.z + a.w) + (b.x + b.y + b.z + b.w);
#pragma unroll
  for (int off = 32; off > 0; off >>= 1) s += __shfl_xor(s, off);
  if (lane == 0) reds[w] = s;
  __syncthreads();
  s = reds[0] + reds[1] + reds[2] + reds[3];

  const float inv = 1.0f / s;
  a.x *= inv; a.y *= inv; a.z *= inv; a.w *= inv;
  b.x *= inv; b.y *= inv; b.z *= inv; b.w *= inv;
  rv[t] = a;
  rv[t + 256] = b;
}

extern "C" void kernel_launch(void* const* d_in, const int* in_sizes, int n_in,
                              void* d_out, int out_size, void* d_ws, size_t ws_size,
                              hipStream_t stream) {
  const float* X = (const float*)d_in[0];
  float* out = (float*)d_out;

  const size_t offS = 32u << 20;   // S16 at +32 MB (X8 is 8.4 MB)
  const size_t need = offS + (size_t)NBATCH * NTOK * NTOK * sizeof(short);  // ~99 MB

  if (ws_size >= need) {
    char*  X8  = (char*)d_ws;
    short* S16 = (short*)((char*)d_ws + offS);
    const int n_threads = NBATCH * NTOK * DDIM / 8;
    convert_fp8_kernel<<<n_threads / 256, 256, 0, stream>>>(X, X8);
    // 136 triangular 128x128 tiles x 8 batches; bid&7 = batch (XCD pin)
    scores_fp8_kernel<<<136 * NBATCH, 256, 0, stream>>>(X8, S16);
    softmax_bf16_kernel<<<NBATCH * NTOK, 256, 0, stream>>>(S16, out);
  } else {
    dim3 ggrid(NTOK / 128, NTOK / 128, NBATCH);
    scores_kernel<<<ggrid, 256, 0, stream>>>(X, out);
    softmax_kernel<<<NBATCH * NTOK, 256, 0, stream>>>(out);
  }
}

// Round 16
// 67.111 us; speedup vs baseline: 1.2984x; 1.0402x over previous
//
#include <hip/hip_runtime.h>
#include <hip/hip_bf16.h>
#include <hip/hip_fp16.h>

#define NTOK 2048
#define DDIM 512
#define NBATCH 8

using bf16x8 = __attribute__((ext_vector_type(8))) short;
using f32x4  = __attribute__((ext_vector_type(4))) float;

__device__ __forceinline__ short f2bf(float f) {
  __hip_bfloat16 h = __float2bfloat16(f);
  union { __hip_bfloat16 h; short s; } u; u.h = h;
  return u.s;
}

__device__ __forceinline__ float e5m2tof(unsigned byte) {
  // e5m2 is f16 truncated to its top 8 bits
  union { unsigned short u; __half h; } c;
  c.u = (unsigned short)(byte << 8);
  return __half2float(c.h);
}

__device__ __forceinline__ void async_copy16(void* lds, const void* g) {
  __builtin_amdgcn_global_load_lds(
      (const __attribute__((address_space(1))) void*)g,
      (__attribute__((address_space(3))) void*)lds,
      16, 0, 0);
}

// fp32 -> fp8 e4m3 (OCP) convert: each thread 8 floats -> 8 B store.
__global__ __launch_bounds__(256) void convert_fp8_kernel(const float* __restrict__ X,
                                                          char* __restrict__ Y) {
  const int i = blockIdx.x * 256 + threadIdx.x;
  const float4* xv = reinterpret_cast<const float4*>(X);
  const float4 a = xv[(size_t)i * 2];
  const float4 b = xv[(size_t)i * 2 + 1];
  int lo = __builtin_amdgcn_cvt_pk_fp8_f32(a.x, a.y, 0, false);
  lo     = __builtin_amdgcn_cvt_pk_fp8_f32(a.z, a.w, lo, true);
  int hi = __builtin_amdgcn_cvt_pk_fp8_f32(b.x, b.y, 0, false);
  hi     = __builtin_amdgcn_cvt_pk_fp8_f32(b.z, b.w, hi, true);
  int2 o; o.x = lo; o.y = hi;
  *reinterpret_cast<int2*>(Y + (size_t)i * 8) = o;
}

// Symmetric scores on fp8-e4m3. 128x128 tile, 4 waves (2Mx2N), BK=64
// double-buffered + 16B-chunk XOR swizzle (r15-verified: conflict-free,
// 8 K-steps = half barrier events). Output S in fp8-e5m2 (r14-verified
// numerics: one-hot margin >> underflow threshold). Diag alias B->A.
__global__ __launch_bounds__(256, 4) void scores_fp8_kernel(
    const char* __restrict__ X8, char* __restrict__ S8) {
  int rem = blockIdx.x >> 3;
  int bi = 0;
  while (rem >= 16 - bi) { rem -= 16 - bi; ++bi; }
  const int bj = bi + rem;
  const int b  = blockIdx.x & 7;           // batch -> XCD pin
  const bool diag = (bi == bj);

  const int i0 = bi * 128;
  const int j0 = bj * 128;
  const char* Xb = X8 + (size_t)b * NTOK * DDIM;   // 512 B per row
  char* Sb = S8 + (size_t)b * NTOK * NTOK;         // 1 B per score

  __shared__ char ldsA8[2][128 * 64];      // 8 KB per buf
  __shared__ char ldsB8[2][128 * 64];      // total 32 KB

  const int t    = threadIdx.x;
  const int lane = t & 63;
  const int w    = t >> 6;                 // 0..3
  const int wr   = (w >> 1) * 64;
  const int wc   = (w & 1) * 64;
  const int lr   = lane & 15;
  const int g    = lane >> 4;              // 0..3
  const int s4   = (lr >> 2) & 3;          // read-side swizzle key (row>>2)&3
  const int ko0  = (((g >> 1) ^ s4) * 16) + (g & 1) * 8;
  const int ko1  = (((2 + (g >> 1)) ^ s4) * 16) + (g & 1) * 8;

  f32x4 acc[4][4] = {};

  auto stage8 = [&](int buf, int kt) {
    const int k0 = kt * 64;                // 64 B per row per K-step
#pragma unroll
    for (int q = 0; q < 2; ++q) {
      const int seg  = w * 2 + q;          // 8 segs of 1 KB (16 rows x 64 B)
      const int row  = seg * 16 + (lane >> 2);
      const int csrc = ((lane & 3) ^ ((row >> 2) & 3)) * 16;  // inverse swizzle
      async_copy16(&ldsA8[buf][seg * 1024],
                   Xb + (size_t)(i0 + row) * DDIM + k0 + csrc);
      if (!diag)
        async_copy16(&ldsB8[buf][seg * 1024],
                     Xb + (size_t)(j0 + row) * DDIM + k0 + csrc);
    }
  };

  auto phases8 = [&](int buf) {
    const char* A0 = ldsA8[buf];
    const char* B0 = diag ? ldsA8[buf] : ldsB8[buf];
#pragma unroll
    for (int ks = 0; ks < 2; ++ks) {
      const int ko = ks ? ko1 : ko0;
      long long af0 = *reinterpret_cast<const long long*>(&A0[(wr + 0 * 16 + lr) * 64 + ko]);
      long long af1 = *reinterpret_cast<const long long*>(&A0[(wr + 1 * 16 + lr) * 64 + ko]);
      long long af2 = *reinterpret_cast<const long long*>(&A0[(wr + 2 * 16 + lr) * 64 + ko]);
      long long af3 = *reinterpret_cast<const long long*>(&A0[(wr + 3 * 16 + lr) * 64 + ko]);
      long long bf0 = *reinterpret_cast<const long long*>(&B0[(wc + 0 * 16 + lr) * 64 + ko]);
      long long bf1 = *reinterpret_cast<const long long*>(&B0[(wc + 1 * 16 + lr) * 64 + ko]);
      long long bf2 = *reinterpret_cast<const long long*>(&B0[(wc + 2 * 16 + lr) * 64 + ko]);
      long long bf3 = *reinterpret_cast<const long long*>(&B0[(wc + 3 * 16 + lr) * 64 + ko]);
      __builtin_amdgcn_s_setprio(1);
      acc[0][0] = __builtin_amdgcn_mfma_f32_16x16x32_fp8_fp8(af0, bf0, acc[0][0], 0, 0, 0);
      acc[0][1] = __builtin_amdgcn_mfma_f32_16x16x32_fp8_fp8(af0, bf1, acc[0][1], 0, 0, 0);
      acc[0][2] = __builtin_amdgcn_mfma_f32_16x16x32_fp8_fp8(af0, bf2, acc[0][2], 0, 0, 0);
      acc[0][3] = __builtin_amdgcn_mfma_f32_16x16x32_fp8_fp8(af0, bf3, acc[0][3], 0, 0, 0);
      acc[1][0] = __builtin_amdgcn_mfma_f32_16x16x32_fp8_fp8(af1, bf0, acc[1][0], 0, 0, 0);
      acc[1][1] = __builtin_amdgcn_mfma_f32_16x16x32_fp8_fp8(af1, bf1, acc[1][1], 0, 0, 0);
      acc[1][2] = __builtin_amdgcn_mfma_f32_16x16x32_fp8_fp8(af1, bf2, acc[1][2], 0, 0, 0);
      acc[1][3] = __builtin_amdgcn_mfma_f32_16x16x32_fp8_fp8(af1, bf3, acc[1][3], 0, 0, 0);
      acc[2][0] = __builtin_amdgcn_mfma_f32_16x16x32_fp8_fp8(af2, bf0, acc[2][0], 0, 0, 0);
      acc[2][1] = __builtin_amdgcn_mfma_f32_16x16x32_fp8_fp8(af2, bf1, acc[2][1], 0, 0, 0);
      acc[2][2] = __builtin_amdgcn_mfma_f32_16x16x32_fp8_fp8(af2, bf2, acc[2][2], 0, 0, 0);
      acc[2][3] = __builtin_amdgcn_mfma_f32_16x16x32_fp8_fp8(af2, bf3, acc[2][3], 0, 0, 0);
      acc[3][0] = __builtin_amdgcn_mfma_f32_16x16x32_fp8_fp8(af3, bf0, acc[3][0], 0, 0, 0);
      acc[3][1] = __builtin_amdgcn_mfma_f32_16x16x32_fp8_fp8(af3, bf1, acc[3][1], 0, 0, 0);
      acc[3][2] = __builtin_amdgcn_mfma_f32_16x16x32_fp8_fp8(af3, bf2, acc[3][2], 0, 0, 0);
      acc[3][3] = __builtin_amdgcn_mfma_f32_16x16x32_fp8_fp8(af3, bf3, acc[3][3], 0, 0, 0);
      __builtin_amdgcn_s_setprio(0);
    }
  };

  stage8(0, 0);
#pragma unroll
  for (int i = 0; i < 7; ++i) {
    stage8((i + 1) & 1, i + 1);
    if (diag) { asm volatile("s_waitcnt vmcnt(2)" ::: "memory"); }
    else      { asm volatile("s_waitcnt vmcnt(4)" ::: "memory"); }
    __builtin_amdgcn_s_barrier();
    phases8(i & 1);
    __builtin_amdgcn_s_barrier();
  }
  asm volatile("s_waitcnt vmcnt(0)" ::: "memory");
  __builtin_amdgcn_s_barrier();
  phases8(1);

  // epilogue: C/D layout col = lane&15, row = (lane>>4)*4 + reg.
  // Pack 4 row-values to e5m2 (cvt_pk_bf8): byte stores normal, int mirror.
  const int crow = (lane >> 4) * 4;
  const int ccol = lane & 15;

#pragma unroll
  for (int m = 0; m < 4; ++m) {
#pragma unroll
    for (int n = 0; n < 4; ++n) {
      const int gr = i0 + wr + m * 16 + crow;   // multiple of 4
      const int gc = j0 + wc + n * 16 + ccol;
      int pk = __builtin_amdgcn_cvt_pk_bf8_f32(acc[m][n][0], acc[m][n][1], 0, false);
      pk     = __builtin_amdgcn_cvt_pk_bf8_f32(acc[m][n][2], acc[m][n][3], pk, true);
      Sb[(size_t)(gr + 0) * NTOK + gc] = (char)(pk & 0xff);
      Sb[(size_t)(gr + 1) * NTOK + gc] = (char)((pk >> 8) & 0xff);
      Sb[(size_t)(gr + 2) * NTOK + gc] = (char)((pk >> 16) & 0xff);
      Sb[(size_t)(gr + 3) * NTOK + gc] = (char)((pk >> 24) & 0xff);
      if (!diag) {
        // mirror: 4 consecutive cols at row gc -> one aligned int store
        *reinterpret_cast<int*>(Sb + (size_t)gc * NTOK + gr) = pk;
      }
    }
  }
}

// Row softmax: e5m2 scores in, fp32 probabilities out (r14-verified numerics).
__global__ __launch_bounds__(256) void softmax_fp8_kernel(
    const char* __restrict__ S8, float* __restrict__ P) {
  const int b   = blockIdx.x & 7;
  const int row = blockIdx.x >> 3;
  const char* srow = S8 + ((size_t)b * NTOK + row) * NTOK;
  float* prow = P + ((size_t)b * NTOK + row) * NTOK;

  const int t    = threadIdx.x;
  const int lane = t & 63;
  const int w    = t >> 6;

  const int2 h = *reinterpret_cast<const int2*>(srow + t * 8);
  const unsigned lo = (unsigned)h.x, hi = (unsigned)h.y;
  float v[8];
#pragma unroll
  for (int k = 0; k < 4; ++k) {
    v[k]     = e5m2tof((lo >> (8 * k)) & 0xff);
    v[k + 4] = e5m2tof((hi >> (8 * k)) & 0xff);
  }

  float m = v[0];
#pragma unroll
  for (int k = 1; k < 8; ++k) m = fmaxf(m, v[k]);
#pragma unroll
  for (int off = 32; off > 0; off >>= 1) m = fmaxf(m, __shfl_xor(m, off));

  __shared__ float redm[4];
  __shared__ float reds[4];
  if (lane == 0) redm[w] = m;
  __syncthreads();
  m = fmaxf(fmaxf(redm[0], redm[1]), fmaxf(redm[2], redm[3]));

  float s = 0.f;
#pragma unroll
  for (int k = 0; k < 8; ++k) { v[k] = __expf(v[k] - m); s += v[k]; }
#pragma unroll
  for (int off = 32; off > 0; off >>= 1) s += __shfl_xor(s, off);
  if (lane == 0) reds[w] = s;
  __syncthreads();
  s = reds[0] + reds[1] + reds[2] + reds[3];

  const float inv = 1.0f / s;
  f32x4 o0, o1;
#pragma unroll
  for (int k = 0; k < 4; ++k) { o0[k] = v[k] * inv; o1[k] = v[k + 4] * inv; }
  *reinterpret_cast<f32x4*>(prow + t * 8)     = o0;
  *reinterpret_cast<f32x4*>(prow + t * 8 + 4) = o1;
}

// ---------- fallback path (ws too small): round-1 verified kernels ----------
__global__ __launch_bounds__(256) void scores_kernel(const float* __restrict__ X,
                                                     float* __restrict__ S) {
  const int b  = blockIdx.z;
  const int i0 = blockIdx.y * 128;
  const int j0 = blockIdx.x * 128;
  const float* Xb = X + (size_t)b * NTOK * DDIM;
  float* Sb = S + (size_t)b * NTOK * NTOK;

  __shared__ short lds_a[128][64];
  __shared__ short lds_b[128][64];

  const int t    = threadIdx.x;
  const int lane = t & 63;
  const int w    = t >> 6;
  const int wr   = (w >> 1) * 64;
  const int wc   = (w & 1) * 64;
  const int lr   = lane & 15;
  const int lk   = (lane >> 4) * 8;

  f32x4 acc[4][4] = {};

  for (int k0 = 0; k0 < DDIM; k0 += 64) {
#pragma unroll
    for (int q = 0; q < 8; ++q) {
      const int v  = t + 256 * q;
      const int r  = v >> 4;
      const int c4 = (v & 15) * 4;
      const float4 va = *reinterpret_cast<const float4*>(
          Xb + (size_t)(i0 + r) * DDIM + k0 + c4);
      const float4 vb = *reinterpret_cast<const float4*>(
          Xb + (size_t)(j0 + r) * DDIM + k0 + c4);
      short4 sa, sb;
      sa.x = f2bf(va.x); sa.y = f2bf(va.y); sa.z = f2bf(va.z); sa.w = f2bf(va.w);
      sb.x = f2bf(vb.x); sb.y = f2bf(vb.y); sb.z = f2bf(vb.z); sb.w = f2bf(vb.w);
      *reinterpret_cast<short4*>(&lds_a[r][c4]) = sa;
      *reinterpret_cast<short4*>(&lds_b[r][c4]) = sb;
    }
    __syncthreads();

#pragma unroll
    for (int ks = 0; ks < 2; ++ks) {
      bf16x8 af[4], bfr[4];
#pragma unroll
      for (int m = 0; m < 4; ++m)
        af[m] = *reinterpret_cast<const bf16x8*>(&lds_a[wr + m * 16 + lr][ks * 32 + lk]);
#pragma unroll
      for (int n = 0; n < 4; ++n)
        bfr[n] = *reinterpret_cast<const bf16x8*>(&lds_b[wc + n * 16 + lr][ks * 32 + lk]);
#pragma unroll
      for (int m = 0; m < 4; ++m)
#pragma unroll
        for (int n = 0; n < 4; ++n)
          acc[m][n] = __builtin_amdgcn_mfma_f32_16x16x32_bf16(af[m], bfr[n], acc[m][n], 0, 0, 0);
    }
    __syncthreads();
  }

  const int crow = (lane >> 4) * 4;
  const int ccol = lane & 15;
#pragma unroll
  for (int m = 0; m < 4; ++m) {
#pragma unroll
    for (int n = 0; n < 4; ++n) {
      const int gr = i0 + wr + m * 16 + crow;
      const int gc = j0 + wc + n * 16 + ccol;
      float* outp = Sb + (size_t)gr * NTOK + gc;
#pragma unroll
      for (int r = 0; r < 4; ++r)
        outp[(size_t)r * NTOK] = acc[m][n][r];
    }
  }
}

// In-place row softmax: one 256-thread block per row of 2048 fp32.
__global__ __launch_bounds__(256) void softmax_kernel(float* __restrict__ S) {
  float* row = S + (size_t)blockIdx.x * NTOK;
  const int t    = threadIdx.x;
  const int lane = t & 63;
  const int w    = t >> 6;

  float4* rv = reinterpret_cast<float4*>(row);
  float4 a = rv[t];
  float4 b = rv[t + 256];

  float m = fmaxf(fmaxf(fmaxf(a.x, a.y), fmaxf(a.z, a.w)),
                  fmaxf(fmaxf(b.x, b.y), fmaxf(b.z, b.w)));
#pragma unroll
  for (int off = 32; off > 0; off >>= 1) m = fmaxf(m, __shfl_xor(m, off));

  __shared__ float redm[4];
  __shared__ float reds[4];
  if (lane == 0) redm[w] = m;
  __syncthreads();
  m = fmaxf(fmaxf(redm[0], redm[1]), fmaxf(redm[2], redm[3]));

  a.x = __expf(a.x - m); a.y = __expf(a.y - m);
  a.z = __expf(a.z - m); a.w = __expf(a.w - m);
  b.x = __expf(b.x - m); b.y = __expf(b.y - m);
  b.z = __expf(b.z - m); b.w = __expf(b.w - m);

  float s = (a.x + a.y + a.z + a.w) + (b.x + b.y + b.z + b.w);
#pragma unroll
  for (int off = 32; off > 0; off >>= 1) s += __shfl_xor(s, off);
  if (lane == 0) reds[w] = s;
  __syncthreads();
  s = reds[0] + reds[1] + reds[2] + reds[3];

  const float inv = 1.0f / s;
  a.x *= inv; a.y *= inv; a.z *= inv; a.w *= inv;
  b.x *= inv; b.y *= inv; b.z *= inv; b.w *= inv;
  rv[t] = a;
  rv[t + 256] = b;
}

extern "C" void kernel_launch(void* const* d_in, const int* in_sizes, int n_in,
                              void* d_out, int out_size, void* d_ws, size_t ws_size,
                              hipStream_t stream) {
  const float* X = (const float*)d_in[0];
  float* out = (float*)d_out;

  const size_t offS = 32u << 20;   // S8 at +32 MB (X8 is 8.4 MB)
  const size_t need = offS + (size_t)NBATCH * NTOK * NTOK;  // ~66 MB

  if (ws_size >= need) {
    char* X8 = (char*)d_ws;
    char* S8 = (char*)d_ws + offS;
    const int n_threads = NBATCH * NTOK * DDIM / 8;
    convert_fp8_kernel<<<n_threads / 256, 256, 0, stream>>>(X, X8);
    // 136 triangular 128x128 tiles x 8 batches; bid&7 = batch (XCD pin)
    scores_fp8_kernel<<<136 * NBATCH, 256, 0, stream>>>(X8, S8);
    softmax_fp8_kernel<<<NBATCH * NTOK, 256, 0, stream>>>(S8, out);
  } else {
    dim3 ggrid(NTOK / 128, NTOK / 128, NBATCH);
    scores_kernel<<<ggrid, 256, 0, stream>>>(X, out);
    softmax_kernel<<<NBATCH * NTOK, 256, 0, stream>>>(out);
  }
}

// Round 17
// 65.613 us; speedup vs baseline: 1.3280x; 1.0228x over previous
//
#include <hip/hip_runtime.h>
#include <hip/hip_bf16.h>
#include <hip/hip_fp16.h>

#define NTOK 2048
#define DDIM 512
#define NBATCH 8

using bf16x8 = __attribute__((ext_vector_type(8))) short;
using f32x4  = __attribute__((ext_vector_type(4))) float;

__device__ __forceinline__ short f2bf(float f) {
  __hip_bfloat16 h = __float2bfloat16(f);
  union { __hip_bfloat16 h; short s; } u; u.h = h;
  return u.s;
}

__device__ __forceinline__ float e5m2tof(unsigned byte) {
  // e5m2 is f16 truncated to its top 8 bits
  union { unsigned short u; __half h; } c;
  c.u = (unsigned short)(byte << 8);
  return __half2float(c.h);
}

__device__ __forceinline__ void async_copy16(void* lds, const void* g) {
  __builtin_amdgcn_global_load_lds(
      (const __attribute__((address_space(1))) void*)g,
      (__attribute__((address_space(3))) void*)lds,
      16, 0, 0);
}

// fp32 -> fp8 e4m3 (OCP) convert: each thread 8 floats -> 8 B store.
__global__ __launch_bounds__(256) void convert_fp8_kernel(const float* __restrict__ X,
                                                          char* __restrict__ Y) {
  const int i = blockIdx.x * 256 + threadIdx.x;
  const float4* xv = reinterpret_cast<const float4*>(X);
  const float4 a = xv[(size_t)i * 2];
  const float4 b = xv[(size_t)i * 2 + 1];
  int lo = __builtin_amdgcn_cvt_pk_fp8_f32(a.x, a.y, 0, false);
  lo     = __builtin_amdgcn_cvt_pk_fp8_f32(a.z, a.w, lo, true);
  int hi = __builtin_amdgcn_cvt_pk_fp8_f32(b.x, b.y, 0, false);
  hi     = __builtin_amdgcn_cvt_pk_fp8_f32(b.z, b.w, hi, true);
  int2 o; o.x = lo; o.y = hi;
  *reinterpret_cast<int2*>(Y + (size_t)i * 8) = o;
}

// Symmetric scores on fp8-e4m3. 128x128 tile, 4 waves (2Mx2N), BK=64 +
// 16B-chunk XOR swizzle (r15-verified conflict-free). NEW: 3-slot ring,
// prefetch depth 1, ONE barrier per K-step (WAR barrier provably redundant:
// stage at iter i targets slot (i+1)%3, last read at iter i-2; all waves'
// slot-(i-2) ds_reads completed before they arrived at barrier i-1, which
// the staging wave has passed). 8 barriers/block vs r16's 16. LDS 48 KB ->
// 3 blocks/CU. Output S in fp8-e5m2 (r14/r16-verified). Diag alias B->A.
__global__ __launch_bounds__(256, 4) void scores_fp8_kernel(
    const char* __restrict__ X8, char* __restrict__ S8) {
  int rem = blockIdx.x >> 3;
  int bi = 0;
  while (rem >= 16 - bi) { rem -= 16 - bi; ++bi; }
  const int bj = bi + rem;
  const int b  = blockIdx.x & 7;           // batch -> XCD pin
  const bool diag = (bi == bj);

  const int i0 = bi * 128;
  const int j0 = bj * 128;
  const char* Xb = X8 + (size_t)b * NTOK * DDIM;   // 512 B per row
  char* Sb = S8 + (size_t)b * NTOK * NTOK;         // 1 B per score

  __shared__ char ldsA8[3][128 * 64];      // 8 KB per slot, 24 KB
  __shared__ char ldsB8[3][128 * 64];      // total 48 KB

  const int t    = threadIdx.x;
  const int lane = t & 63;
  const int w    = t >> 6;                 // 0..3
  const int wr   = (w >> 1) * 64;
  const int wc   = (w & 1) * 64;
  const int lr   = lane & 15;
  const int g    = lane >> 4;              // 0..3
  const int s4   = (lr >> 2) & 3;          // read-side swizzle key (row>>2)&3
  const int ko0  = (((g >> 1) ^ s4) * 16) + (g & 1) * 8;
  const int ko1  = (((2 + (g >> 1)) ^ s4) * 16) + (g & 1) * 8;

  f32x4 acc[4][4] = {};

  auto stage8 = [&](int slot, int kt) {
    const int k0 = kt * 64;                // 64 B per row per K-step
#pragma unroll
    for (int q = 0; q < 2; ++q) {
      const int seg  = w * 2 + q;          // 8 segs of 1 KB (16 rows x 64 B)
      const int row  = seg * 16 + (lane >> 2);
      const int csrc = ((lane & 3) ^ ((row >> 2) & 3)) * 16;  // inverse swizzle
      async_copy16(&ldsA8[slot][seg * 1024],
                   Xb + (size_t)(i0 + row) * DDIM + k0 + csrc);
      if (!diag)
        async_copy16(&ldsB8[slot][seg * 1024],
                     Xb + (size_t)(j0 + row) * DDIM + k0 + csrc);
    }
  };

  auto phases8 = [&](int slot) {
    const char* A0 = ldsA8[slot];
    const char* B0 = diag ? ldsA8[slot] : ldsB8[slot];
#pragma unroll
    for (int ks = 0; ks < 2; ++ks) {
      const int ko = ks ? ko1 : ko0;
      long long af0 = *reinterpret_cast<const long long*>(&A0[(wr + 0 * 16 + lr) * 64 + ko]);
      long long af1 = *reinterpret_cast<const long long*>(&A0[(wr + 1 * 16 + lr) * 64 + ko]);
      long long af2 = *reinterpret_cast<const long long*>(&A0[(wr + 2 * 16 + lr) * 64 + ko]);
      long long af3 = *reinterpret_cast<const long long*>(&A0[(wr + 3 * 16 + lr) * 64 + ko]);
      long long bf0 = *reinterpret_cast<const long long*>(&B0[(wc + 0 * 16 + lr) * 64 + ko]);
      long long bf1 = *reinterpret_cast<const long long*>(&B0[(wc + 1 * 16 + lr) * 64 + ko]);
      long long bf2 = *reinterpret_cast<const long long*>(&B0[(wc + 2 * 16 + lr) * 64 + ko]);
      long long bf3 = *reinterpret_cast<const long long*>(&B0[(wc + 3 * 16 + lr) * 64 + ko]);
      __builtin_amdgcn_s_setprio(1);
      acc[0][0] = __builtin_amdgcn_mfma_f32_16x16x32_fp8_fp8(af0, bf0, acc[0][0], 0, 0, 0);
      acc[0][1] = __builtin_amdgcn_mfma_f32_16x16x32_fp8_fp8(af0, bf1, acc[0][1], 0, 0, 0);
      acc[0][2] = __builtin_amdgcn_mfma_f32_16x16x32_fp8_fp8(af0, bf2, acc[0][2], 0, 0, 0);
      acc[0][3] = __builtin_amdgcn_mfma_f32_16x16x32_fp8_fp8(af0, bf3, acc[0][3], 0, 0, 0);
      acc[1][0] = __builtin_amdgcn_mfma_f32_16x16x32_fp8_fp8(af1, bf0, acc[1][0], 0, 0, 0);
      acc[1][1] = __builtin_amdgcn_mfma_f32_16x16x32_fp8_fp8(af1, bf1, acc[1][1], 0, 0, 0);
      acc[1][2] = __builtin_amdgcn_mfma_f32_16x16x32_fp8_fp8(af1, bf2, acc[1][2], 0, 0, 0);
      acc[1][3] = __builtin_amdgcn_mfma_f32_16x16x32_fp8_fp8(af1, bf3, acc[1][3], 0, 0, 0);
      acc[2][0] = __builtin_amdgcn_mfma_f32_16x16x32_fp8_fp8(af2, bf0, acc[2][0], 0, 0, 0);
      acc[2][1] = __builtin_amdgcn_mfma_f32_16x16x32_fp8_fp8(af2, bf1, acc[2][1], 0, 0, 0);
      acc[2][2] = __builtin_amdgcn_mfma_f32_16x16x32_fp8_fp8(af2, bf2, acc[2][2], 0, 0, 0);
      acc[2][3] = __builtin_amdgcn_mfma_f32_16x16x32_fp8_fp8(af2, bf3, acc[2][3], 0, 0, 0);
      acc[3][0] = __builtin_amdgcn_mfma_f32_16x16x32_fp8_fp8(af3, bf0, acc[3][0], 0, 0, 0);
      acc[3][1] = __builtin_amdgcn_mfma_f32_16x16x32_fp8_fp8(af3, bf1, acc[3][1], 0, 0, 0);
      acc[3][2] = __builtin_amdgcn_mfma_f32_16x16x32_fp8_fp8(af3, bf2, acc[3][2], 0, 0, 0);
      acc[3][3] = __builtin_amdgcn_mfma_f32_16x16x32_fp8_fp8(af3, bf3, acc[3][3], 0, 0, 0);
      __builtin_amdgcn_s_setprio(0);
    }
  };

  // prologue: stage kt=0 into slot 0 (prefetch depth 1)
  stage8(0, 0);
#pragma unroll
  for (int i = 0; i < 8; ++i) {
    if (i + 1 < 8) {
      stage8((i + 1) % 3, i + 1);          // issue next-tile loads first
      if (diag) { asm volatile("s_waitcnt vmcnt(2)" ::: "memory"); }
      else      { asm volatile("s_waitcnt vmcnt(4)" ::: "memory"); }
    } else {
      asm volatile("s_waitcnt vmcnt(0)" ::: "memory");
    }
    __builtin_amdgcn_s_barrier();          // slot i visible to all waves
    phases8(i % 3);                        // single barrier per K-step
  }

  // epilogue: C/D layout col = lane&15, row = (lane>>4)*4 + reg.
  // Pack 4 row-values to e5m2 (cvt_pk_bf8): byte stores normal, int mirror.
  const int crow = (lane >> 4) * 4;
  const int ccol = lane & 15;

#pragma unroll
  for (int m = 0; m < 4; ++m) {
#pragma unroll
    for (int n = 0; n < 4; ++n) {
      const int gr = i0 + wr + m * 16 + crow;   // multiple of 4
      const int gc = j0 + wc + n * 16 + ccol;
      int pk = __builtin_amdgcn_cvt_pk_bf8_f32(acc[m][n][0], acc[m][n][1], 0, false);
      pk     = __builtin_amdgcn_cvt_pk_bf8_f32(acc[m][n][2], acc[m][n][3], pk, true);
      Sb[(size_t)(gr + 0) * NTOK + gc] = (char)(pk & 0xff);
      Sb[(size_t)(gr + 1) * NTOK + gc] = (char)((pk >> 8) & 0xff);
      Sb[(size_t)(gr + 2) * NTOK + gc] = (char)((pk >> 16) & 0xff);
      Sb[(size_t)(gr + 3) * NTOK + gc] = (char)((pk >> 24) & 0xff);
      if (!diag) {
        // mirror: 4 consecutive cols at row gc -> one aligned int store
        *reinterpret_cast<int*>(Sb + (size_t)gc * NTOK + gr) = pk;
      }
    }
  }
}

// Row softmax: e5m2 scores in, fp32 probabilities out (r14/r16-verified).
__global__ __launch_bounds__(256) void softmax_fp8_kernel(
    const char* __restrict__ S8, float* __restrict__ P) {
  const int b   = blockIdx.x & 7;
  const int row = blockIdx.x >> 3;
  const char* srow = S8 + ((size_t)b * NTOK + row) * NTOK;
  float* prow = P + ((size_t)b * NTOK + row) * NTOK;

  const int t    = threadIdx.x;
  const int lane = t & 63;
  const int w    = t >> 6;

  const int2 h = *reinterpret_cast<const int2*>(srow + t * 8);
  const unsigned lo = (unsigned)h.x, hi = (unsigned)h.y;
  float v[8];
#pragma unroll
  for (int k = 0; k < 4; ++k) {
    v[k]     = e5m2tof((lo >> (8 * k)) & 0xff);
    v[k + 4] = e5m2tof((hi >> (8 * k)) & 0xff);
  }

  float m = v[0];
#pragma unroll
  for (int k = 1; k < 8; ++k) m = fmaxf(m, v[k]);
#pragma unroll
  for (int off = 32; off > 0; off >>= 1) m = fmaxf(m, __shfl_xor(m, off));

  __shared__ float redm[4];
  __shared__ float reds[4];
  if (lane == 0) redm[w] = m;
  __syncthreads();
  m = fmaxf(fmaxf(redm[0], redm[1]), fmaxf(redm[2], redm[3]));

  float s = 0.f;
#pragma unroll
  for (int k = 0; k < 8; ++k) { v[k] = __expf(v[k] - m); s += v[k]; }
#pragma unroll
  for (int off = 32; off > 0; off >>= 1) s += __shfl_xor(s, off);
  if (lane == 0) reds[w] = s;
  __syncthreads();
  s = reds[0] + reds[1] + reds[2] + reds[3];

  const float inv = 1.0f / s;
  f32x4 o0, o1;
#pragma unroll
  for (int k = 0; k < 4; ++k) { o0[k] = v[k] * inv; o1[k] = v[k + 4] * inv; }
  *reinterpret_cast<f32x4*>(prow + t * 8)     = o0;
  *reinterpret_cast<f32x4*>(prow + t * 8 + 4) = o1;
}

// ---------- fallback path (ws too small): round-1 verified kernels ----------
__global__ __launch_bounds__(256) void scores_kernel(const float* __restrict__ X,
                                                     float* __restrict__ S) {
  const int b  = blockIdx.z;
  const int i0 = blockIdx.y * 128;
  const int j0 = blockIdx.x * 128;
  const float* Xb = X + (size_t)b * NTOK * DDIM;
  float* Sb = S + (size_t)b * NTOK * NTOK;

  __shared__ short lds_a[128][64];
  __shared__ short lds_b[128][64];

  const int t    = threadIdx.x;
  const int lane = t & 63;
  const int w    = t >> 6;
  const int wr   = (w >> 1) * 64;
  const int wc   = (w & 1) * 64;
  const int lr   = lane & 15;
  const int lk   = (lane >> 4) * 8;

  f32x4 acc[4][4] = {};

  for (int k0 = 0; k0 < DDIM; k0 += 64) {
#pragma unroll
    for (int q = 0; q < 8; ++q) {
      const int v  = t + 256 * q;
      const int r  = v >> 4;
      const int c4 = (v & 15) * 4;
      const float4 va = *reinterpret_cast<const float4*>(
          Xb + (size_t)(i0 + r) * DDIM + k0 + c4);
      const float4 vb = *reinterpret_cast<const float4*>(
          Xb + (size_t)(j0 + r) * DDIM + k0 + c4);
      short4 sa, sb;
      sa.x = f2bf(va.x); sa.y = f2bf(va.y); sa.z = f2bf(va.z); sa.w = f2bf(va.w);
      sb.x = f2bf(vb.x); sb.y = f2bf(vb.y); sb.z = f2bf(vb.z); sb.w = f2bf(vb.w);
      *reinterpret_cast<short4*>(&lds_a[r][c4]) = sa;
      *reinterpret_cast<short4*>(&lds_b[r][c4]) = sb;
    }
    __syncthreads();

#pragma unroll
    for (int ks = 0; ks < 2; ++ks) {
      bf16x8 af[4], bfr[4];
#pragma unroll
      for (int m = 0; m < 4; ++m)
        af[m] = *reinterpret_cast<const bf16x8*>(&lds_a[wr + m * 16 + lr][ks * 32 + lk]);
#pragma unroll
      for (int n = 0; n < 4; ++n)
        bfr[n] = *reinterpret_cast<const bf16x8*>(&lds_b[wc + n * 16 + lr][ks * 32 + lk]);
#pragma unroll
      for (int m = 0; m < 4; ++m)
#pragma unroll
        for (int n = 0; n < 4; ++n)
          acc[m][n] = __builtin_amdgcn_mfma_f32_16x16x32_bf16(af[m], bfr[n], acc[m][n], 0, 0, 0);
    }
    __syncthreads();
  }

  const int crow = (lane >> 4) * 4;
  const int ccol = lane & 15;
#pragma unroll
  for (int m = 0; m < 4; ++m) {
#pragma unroll
    for (int n = 0; n < 4; ++n) {
      const int gr = i0 + wr + m * 16 + crow;
      const int gc = j0 + wc + n * 16 + ccol;
      float* outp = Sb + (size_t)gr * NTOK + gc;
#pragma unroll
      for (int r = 0; r < 4; ++r)
        outp[(size_t)r * NTOK] = acc[m][n][r];
    }
  }
}

// In-place row softmax: one 256-thread block per row of 2048 fp32.
__global__ __launch_bounds__(256) void softmax_kernel(float* __restrict__ S) {
  float* row = S + (size_t)blockIdx.x * NTOK;
  const int t    = threadIdx.x;
  const int lane = t & 63;
  const int w    = t >> 6;

  float4* rv = reinterpret_cast<float4*>(row);
  float4 a = rv[t];
  float4 b = rv[t + 256];

  float m = fmaxf(fmaxf(fmaxf(a.x, a.y), fmaxf(a.z, a.w)),
                  fmaxf(fmaxf(b.x, b.y), fmaxf(b.z, b.w)));
#pragma unroll
  for (int off = 32; off > 0; off >>= 1) m = fmaxf(m, __shfl_xor(m, off));

  __shared__ float redm[4];
  __shared__ float reds[4];
  if (lane == 0) redm[w] = m;
  __syncthreads();
  m = fmaxf(fmaxf(redm[0], redm[1]), fmaxf(redm[2], redm[3]));

  a.x = __expf(a.x - m); a.y = __expf(a.y - m);
  a.z = __expf(a.z - m); a.w = __expf(a.w - m);
  b.x = __expf(b.x - m); b.y = __expf(b.y - m);
  b.z = __expf(b.z - m); b.w = __expf(b.w - m);

  float s = (a.x + a.y + a.z + a.w) + (b.x + b.y + b.z + b.w);
#pragma unroll
  for (int off = 32; off > 0; off >>= 1) s += __shfl_xor(s, off);
  if (lane == 0) reds[w] = s;
  __syncthreads();
  s = reds[0] + reds[1] + reds[2] + reds[3];

  const float inv = 1.0f / s;
  a.x *= inv; a.y *= inv; a.z *= inv; a.w *= inv;
  b.x *= inv; b.y *= inv; b.z *= inv; b.w *= inv;
  rv[t] = a;
  rv[t + 256] = b;
}

extern "C" void kernel_launch(void* const* d_in, const int* in_sizes, int n_in,
                              void* d_out, int out_size, void* d_ws, size_t ws_size,
                              hipStream_t stream) {
  const float* X = (const float*)d_in[0];
  float* out = (float*)d_out;

  const size_t offS = 32u << 20;   // S8 at +32 MB (X8 is 8.4 MB)
  const size_t need = offS + (size_t)NBATCH * NTOK * NTOK;  // ~66 MB

  if (ws_size >= need) {
    char* X8 = (char*)d_ws;
    char* S8 = (char*)d_ws + offS;
    const int n_threads = NBATCH * NTOK * DDIM / 8;
    convert_fp8_kernel<<<n_threads / 256, 256, 0, stream>>>(X, X8);
    // 136 triangular 128x128 tiles x 8 batches; bid&7 = batch (XCD pin)
    scores_fp8_kernel<<<136 * NBATCH, 256, 0, stream>>>(X8, S8);
    softmax_fp8_kernel<<<NBATCH * NTOK, 256, 0, stream>>>(S8, out);
  } else {
    dim3 ggrid(NTOK / 128, NTOK / 128, NBATCH);
    scores_kernel<<<ggrid, 256, 0, stream>>>(X, out);
    softmax_kernel<<<NBATCH * NTOK, 256, 0, stream>>>(out);
  }
}